// Round 8
// baseline (239.446 us; speedup 1.0000x reference)
//
#include <hip/hip_runtime.h>
#include <hip/hip_bf16.h>
#include <stdint.h>

#define B_    4
#define L_    2048
#define T_    8192      // B*L tokens
#define D_    1024
#define E_    8
#define H_    512

typedef __bf16  bf16x8 __attribute__((ext_vector_type(8)));
typedef float   f32x4  __attribute__((ext_vector_type(4)));
typedef unsigned short ushort_t;

__device__ __forceinline__ ushort_t f2bf(float f) {
    union { float f; unsigned u; } v; v.f = f;
    unsigned u = v.u;
    unsigned r = (u + 0x7fffu + ((u >> 16) & 1u)) >> 16;   // RNE
    return (ushort_t)r;
}

__device__ __forceinline__ float gelu_exact(float v) {
    return 0.5f * v * (1.0f + erff(v * 0.70710678118654752f));
}

// async global->LDS, 16B per lane; LDS dest = wave-uniform base + lane*16
__device__ __forceinline__ void gld_lds16(const void* g, void* l) {
    __attribute__((address_space(3))) uint32_t* lp =
        reinterpret_cast<__attribute__((address_space(3))) uint32_t*>(
            reinterpret_cast<uintptr_t>(l));
    const __attribute__((address_space(1))) uint32_t* gp =
        reinterpret_cast<const __attribute__((address_space(1))) uint32_t*>(
            reinterpret_cast<uintptr_t>(g));
    __builtin_amdgcn_global_load_lds(gp, lp, 16, 0, 0);
}

// ---------------------------------------------------------------------------
// Transpose + fp32->bf16:  in [nmat][R][C] f32 -> out [nmat][C][R] bf16
// ---------------------------------------------------------------------------
__global__ __launch_bounds__(256) void transpose_cvt(
    const float* __restrict__ in, ushort_t* __restrict__ out, int R, int C)
{
    __shared__ float tile[32][33];
    const size_t matoff = (size_t)blockIdx.z * R * C;
    const float* src = in + matoff;
    ushort_t* dst = out + matoff;
    const int r0 = blockIdx.y * 32, c0 = blockIdx.x * 32;
    const int tid = threadIdx.x;
    const int lr = tid >> 3;
    const int lc = (tid & 7) * 4;
    float4 v = *(const float4*)(src + (size_t)(r0 + lr) * C + c0 + lc);
    tile[lr][lc+0] = v.x; tile[lr][lc+1] = v.y;
    tile[lr][lc+2] = v.z; tile[lr][lc+3] = v.w;
    __syncthreads();
    ushort4 o;
    o.x = f2bf(tile[lc+0][lr]);
    o.y = f2bf(tile[lc+1][lr]);
    o.z = f2bf(tile[lc+2][lr]);
    o.w = f2bf(tile[lc+3][lr]);
    *(ushort4*)(dst + (size_t)(c0 + lr) * R + r0 + lc) = o;
}

// ---------------------------------------------------------------------------
// Gating phase 1 + x fp32->bf16 conversion. One wave/token. No atomics.
// ---------------------------------------------------------------------------
__global__ __launch_bounds__(256) void gating_kernel(
    const float* __restrict__ x, const float* __restrict__ gw,
    const float* __restrict__ gb,
    int* __restrict__ eidx, float* __restrict__ gsel, ushort_t* __restrict__ xbf)
{
    const int wave = threadIdx.x >> 6;
    const int lane = threadIdx.x & 63;
    const int t = blockIdx.x * 4 + wave;
    const float* xr = x + (size_t)t * D_;
    ushort_t* xbr = xbf + (size_t)t * D_;

    float acc[E_];
    #pragma unroll
    for (int e = 0; e < E_; ++e) acc[e] = 0.f;

    #pragma unroll
    for (int j = 0; j < 4; ++j) {
        const int d = j * 256 + lane * 4;
        float4 xv = *(const float4*)(xr + d);
        ushort4 o;
        o.x = f2bf(xv.x); o.y = f2bf(xv.y); o.z = f2bf(xv.z); o.w = f2bf(xv.w);
        *(ushort4*)(xbr + d) = o;
        const float* gr = gw + (size_t)d * E_;
        float xs[4] = {xv.x, xv.y, xv.z, xv.w};
        #pragma unroll
        for (int c = 0; c < 4; ++c) {
            float4 g0 = *(const float4*)(gr + c * 8);
            float4 g1 = *(const float4*)(gr + c * 8 + 4);
            acc[0] += xs[c] * g0.x; acc[1] += xs[c] * g0.y;
            acc[2] += xs[c] * g0.z; acc[3] += xs[c] * g0.w;
            acc[4] += xs[c] * g1.x; acc[5] += xs[c] * g1.y;
            acc[6] += xs[c] * g1.z; acc[7] += xs[c] * g1.w;
        }
    }
    #pragma unroll
    for (int s = 1; s < 64; s <<= 1) {
        #pragma unroll
        for (int e = 0; e < E_; ++e)
            acc[e] += __shfl_xor(acc[e], s, 64);
    }
    if (lane == 0) {
        float v[E_];
        #pragma unroll
        for (int e = 0; e < E_; ++e) v[e] = acc[e] + gb[e];
        int i0 = 0;
        #pragma unroll
        for (int e = 1; e < E_; ++e) if (v[e] > v[i0]) i0 = e;
        int i1 = (i0 == 0) ? 1 : 0;
        #pragma unroll
        for (int e = 0; e < E_; ++e) if (e != i0 && v[e] > v[i1]) i1 = e;
        float g0 = 1.f / (1.f + expf(v[i1] - v[i0]));
        eidx[t] = i0 | (i1 << 8);
        gsel[t] = g0;
    }
}

// ---------------------------------------------------------------------------
// Gating phase 2: bucketize (8 global atomics/block) + pack (expert,pos) x2.
// ---------------------------------------------------------------------------
__global__ __launch_bounds__(256) void bucket_kernel(
    const int* __restrict__ eidx, const float* __restrict__ gsel,
    int* __restrict__ counts, int* __restrict__ btok, float* __restrict__ bgate,
    uint32_t* __restrict__ tpos)
{
    __shared__ int lcnt[E_];
    __shared__ int lbase[E_];
    const int tid = threadIdx.x;
    if (tid < E_) lcnt[tid] = 0;
    __syncthreads();
    const int t = blockIdx.x * 256 + tid;
    const int pk = eidx[t];
    const float g0 = gsel[t];
    const int i0 = pk & 0xff, i1 = (pk >> 8) & 0xff;
    const int p0 = atomicAdd(&lcnt[i0], 1);
    const int p1 = atomicAdd(&lcnt[i1], 1);
    __syncthreads();
    if (tid < E_) lbase[tid] = atomicAdd(&counts[tid], lcnt[tid]);
    __syncthreads();
    const int q0 = lbase[i0] + p0, q1 = lbase[i1] + p1;
    btok[i0 * T_ + q0] = t; bgate[i0 * T_ + q0] = g0;
    btok[i1 * T_ + q1] = t; bgate[i1 * T_ + q1] = 1.f - g0;
    tpos[t] = (uint32_t)((i0 << 13) | q0) | ((uint32_t)((i1 << 13) | q1) << 16);
}

__global__ void prefix_kernel(const int* __restrict__ counts, int* __restrict__ offsets)
{
    if (threadIdx.x == 0 && blockIdx.x == 0) {
        int s = 0;
        for (int e = 0; e < E_; ++e) { offsets[e] = s; s += counts[e]; }
    }
}

// ---------------------------------------------------------------------------
// Layer 1: gathered xbf [n_e,1024] @ W1t[e] ([H][D]) -> gelu -> hbuf bf16
// 64x128 tile, BK=128 (half the barrier drains vs BK=64), single-buffered.
// LDS: A 16KB + B 32KB = 48KB -> 3 blocks/CU. Row stride 256B, 16 col-groups,
// XOR swizzle grp ^= row&15 (<=2-way bank alias = free).
// grid: (T_/64=128, H/128=4, E)
// ---------------------------------------------------------------------------
__global__ __launch_bounds__(256) void mlp1_kernel(
    const ushort_t* __restrict__ xbf, const ushort_t* __restrict__ w1t,
    const float* __restrict__ b1,
    const int* __restrict__ counts, const int* __restrict__ offsets,
    const int* __restrict__ btok, ushort_t* __restrict__ hbuf)
{
    const int e   = blockIdx.z;
    const int n_e = counts[e];
    const int m0  = blockIdx.x * 64;
    if (m0 >= n_e) return;
    const int n0  = blockIdx.y * 128;
    const int off = offsets[e];

    __shared__ ushort_t As[64 * 128];    // 16 KB
    __shared__ ushort_t Bs[128 * 128];   // 32 KB

    const int tid  = threadIdx.x;
    const int lane = tid & 63;
    const int wave = tid >> 6;

    // staging: one gld_lds16 instr covers 4 rows x 256B; lane -> (row, group)
    const int srow4 = lane >> 4;          // row within 4-row span
    const int rmod  = wave * 4 + srow4;   // == tile_row & 15 for every instr
    const int cg    = (lane & 15) ^ rmod; // swizzled global col group (16B)

    const ushort_t* aptr[4];
    #pragma unroll
    for (int i = 0; i < 4; ++i) {
        int m = m0 + i * 16 + rmod;
        int tok = btok[e * T_ + (m < n_e ? m : n_e - 1)];
        aptr[i] = xbf + (size_t)tok * D_ + cg * 8;
    }
    const ushort_t* w1e = w1t + (size_t)e * (H_ * D_);
    const ushort_t* bptr[8];
    #pragma unroll
    for (int i = 0; i < 8; ++i)
        bptr[i] = w1e + (size_t)(n0 + i * 16 + rmod) * D_ + cg * 8;

    char* aldst = (char*)As + (wave << 10);   // + i*4096
    char* bldst = (char*)Bs + (wave << 10);

    const int fm   = lane & 15;
    const int quad = lane >> 4;
    const int wm   = (wave & 1) * 32;     // 2 waves over M=64
    const int wn   = (wave >> 1) * 64;    // 2 waves over N=128

    f32x4 acc[2][4];
    #pragma unroll
    for (int i = 0; i < 2; ++i)
        #pragma unroll
        for (int j = 0; j < 4; ++j)
            { acc[i][j][0]=0.f; acc[i][j][1]=0.f; acc[i][j][2]=0.f; acc[i][j][3]=0.f; }

    for (int k0 = 0; k0 < D_; k0 += 128) {
        #pragma unroll
        for (int i = 0; i < 4; ++i)
            gld_lds16(aptr[i] + k0, aldst + (i << 12));
        #pragma unroll
        for (int i = 0; i < 8; ++i)
            gld_lds16(bptr[i] + k0, bldst + (i << 12));
        __syncthreads();
        #pragma unroll
        for (int kk = 0; kk < 4; ++kk) {
            const int grp = kk * 4 + quad;
            bf16x8 af[2], bfr[4];
            #pragma unroll
            for (int i = 0; i < 2; ++i) {
                int ra = wm + i * 16 + fm;
                af[i]  = *(const bf16x8*)((const char*)As + ra * 256 + ((grp ^ (ra & 15)) << 4));
            }
            #pragma unroll
            for (int j = 0; j < 4; ++j) {
                int rb = wn + j * 16 + fm;
                bfr[j] = *(const bf16x8*)((const char*)Bs + rb * 256 + ((grp ^ (rb & 15)) << 4));
            }
            #pragma unroll
            for (int i = 0; i < 2; ++i)
                #pragma unroll
                for (int j = 0; j < 4; ++j)
                    acc[i][j] = __builtin_amdgcn_mfma_f32_16x16x32_bf16(af[i], bfr[j], acc[i][j], 0, 0, 0);
        }
        __syncthreads();
    }

    float bcol[4];
    #pragma unroll
    for (int j = 0; j < 4; ++j)
        bcol[j] = b1[e * H_ + n0 + wn + j * 16 + fm];
    #pragma unroll
    for (int i = 0; i < 2; ++i) {
        #pragma unroll
        for (int r = 0; r < 4; ++r) {
            int m = m0 + wm + i * 16 + quad * 4 + r;
            if (m >= n_e) continue;
            ushort_t* hrow = hbuf + (size_t)(off + m) * H_ + n0;
            #pragma unroll
            for (int j = 0; j < 4; ++j)
                hrow[wn + j * 16 + fm] = f2bf(gelu_exact(acc[i][j][r] + bcol[j]));
        }
    }
}

// ---------------------------------------------------------------------------
// Layer 2: hbuf [n_e,512] @ W2t[e] ([D][H]) -> (acc+b2)*gate -> obuf bf16
// 64x128 tile, BK=128, single-buffered, plain stores. grid: (128, D/128=8, E)
// ---------------------------------------------------------------------------
__global__ __launch_bounds__(256) void mlp2_kernel(
    const ushort_t* __restrict__ hbuf, const ushort_t* __restrict__ w2t,
    const float* __restrict__ b2,
    const int* __restrict__ counts, const int* __restrict__ offsets,
    const float* __restrict__ bgate, ushort_t* __restrict__ obuf)
{
    const int e   = blockIdx.z;
    const int n_e = counts[e];
    const int m0  = blockIdx.x * 64;
    if (m0 >= n_e) return;
    const int n0  = blockIdx.y * 128;
    const int off = offsets[e];

    __shared__ ushort_t As[64 * 128];
    __shared__ ushort_t Bs[128 * 128];

    const int tid  = threadIdx.x;
    const int lane = tid & 63;
    const int wave = tid >> 6;

    const int srow4 = lane >> 4;
    const int rmod  = wave * 4 + srow4;
    const int cg    = (lane & 15) ^ rmod;

    const ushort_t* aptr[4];
    #pragma unroll
    for (int i = 0; i < 4; ++i)
        aptr[i] = hbuf + (size_t)(off + m0 + i * 16 + rmod) * H_ + cg * 8;  // slack rows ok
    const ushort_t* w2e = w2t + (size_t)e * (D_ * H_);
    const ushort_t* bptr[8];
    #pragma unroll
    for (int i = 0; i < 8; ++i)
        bptr[i] = w2e + (size_t)(n0 + i * 16 + rmod) * H_ + cg * 8;

    char* aldst = (char*)As + (wave << 10);
    char* bldst = (char*)Bs + (wave << 10);

    const int fm   = lane & 15;
    const int quad = lane >> 4;
    const int wm   = (wave & 1) * 32;
    const int wn   = (wave >> 1) * 64;

    f32x4 acc[2][4];
    #pragma unroll
    for (int i = 0; i < 2; ++i)
        #pragma unroll
        for (int j = 0; j < 4; ++j)
            { acc[i][j][0]=0.f; acc[i][j][1]=0.f; acc[i][j][2]=0.f; acc[i][j][3]=0.f; }

    for (int k0 = 0; k0 < H_; k0 += 128) {
        #pragma unroll
        for (int i = 0; i < 4; ++i)
            gld_lds16(aptr[i] + k0, aldst + (i << 12));
        #pragma unroll
        for (int i = 0; i < 8; ++i)
            gld_lds16(bptr[i] + k0, bldst + (i << 12));
        __syncthreads();
        #pragma unroll
        for (int kk = 0; kk < 4; ++kk) {
            const int grp = kk * 4 + quad;
            bf16x8 af[2], bfr[4];
            #pragma unroll
            for (int i = 0; i < 2; ++i) {
                int ra = wm + i * 16 + fm;
                af[i]  = *(const bf16x8*)((const char*)As + ra * 256 + ((grp ^ (ra & 15)) << 4));
            }
            #pragma unroll
            for (int j = 0; j < 4; ++j) {
                int rb = wn + j * 16 + fm;
                bfr[j] = *(const bf16x8*)((const char*)Bs + rb * 256 + ((grp ^ (rb & 15)) << 4));
            }
            #pragma unroll
            for (int i = 0; i < 2; ++i)
                #pragma unroll
                for (int j = 0; j < 4; ++j)
                    acc[i][j] = __builtin_amdgcn_mfma_f32_16x16x32_bf16(af[i], bfr[j], acc[i][j], 0, 0, 0);
        }
        __syncthreads();
    }

    float bcol[4];
    #pragma unroll
    for (int j = 0; j < 4; ++j)
        bcol[j] = b2[e * D_ + n0 + wn + j * 16 + fm];
    #pragma unroll
    for (int i = 0; i < 2; ++i) {
        #pragma unroll
        for (int r = 0; r < 4; ++r) {
            int m = m0 + wm + i * 16 + quad * 4 + r;
            if (m >= n_e) continue;
            float g = bgate[e * T_ + m];
            ushort_t* orow = obuf + (size_t)(off + m) * D_ + n0;
            #pragma unroll
            for (int j = 0; j < 4; ++j)
                orow[wn + j * 16 + fm] = f2bf((acc[i][j][r] + bcol[j]) * g);
        }
    }
}

// ---------------------------------------------------------------------------
// Combine: out[t] = obuf[slot0(t)] + obuf[slot1(t)].  2 tokens per block.
// ---------------------------------------------------------------------------
__global__ __launch_bounds__(256) void combine_kernel(
    const ushort_t* __restrict__ obuf, const uint32_t* __restrict__ tpos,
    const int* __restrict__ offsets, float* __restrict__ out)
{
    const int tid = threadIdx.x;
    const int t = blockIdx.x * 2 + (tid >> 7);
    const int c = (tid & 127) * 8;
    const uint32_t pk = tpos[t];
    const int e0 = (pk >> 13) & 7, p0 = pk & 0x1fff;
    const int e1 = (pk >> 29) & 7, p1 = (pk >> 16) & 0x1fff;
    const size_t s0 = (size_t)(offsets[e0] + p0) * D_ + c;
    const size_t s1 = (size_t)(offsets[e1] + p1) * D_ + c;
    bf16x8 a = *(const bf16x8*)(obuf + s0);
    bf16x8 b = *(const bf16x8*)(obuf + s1);
    float4 o0, o1;
    o0.x = (float)a[0] + (float)b[0];
    o0.y = (float)a[1] + (float)b[1];
    o0.z = (float)a[2] + (float)b[2];
    o0.w = (float)a[3] + (float)b[3];
    o1.x = (float)a[4] + (float)b[4];
    o1.y = (float)a[5] + (float)b[5];
    o1.z = (float)a[6] + (float)b[6];
    o1.w = (float)a[7] + (float)b[7];
    float* orow = out + (size_t)t * D_ + c;
    *(float4*)(orow)     = o0;
    *(float4*)(orow + 4) = o1;
}

// ---------------------------------------------------------------------------
extern "C" void kernel_launch(void* const* d_in, const int* in_sizes, int n_in,
                              void* d_out, int out_size, void* d_ws, size_t ws_size,
                              hipStream_t stream)
{
    const float* x  = (const float*)d_in[0];
    const float* gw = (const float*)d_in[1];
    const float* gb = (const float*)d_in[2];
    const float* w1 = (const float*)d_in[3];
    const float* b1 = (const float*)d_in[4];
    const float* w2 = (const float*)d_in[5];
    const float* b2 = (const float*)d_in[6];
    float* out = (float*)d_out;

    // workspace layout
    char* ws = (char*)d_ws;
    int*   counts  = (int*)ws;                                   // 8 ints
    int*   offsets = counts + 8;
    int*   btok    = (int*)(ws + 256);                           // E*T ints
    float* bgate   = (float*)(ws + 256 + (size_t)E_*T_*4);
    size_t p = 256 + 2ull * E_ * T_ * 4;
    int*      eidx = (int*)(ws + p);      p += (size_t)T_ * 4;
    float*    gsel = (float*)(ws + p);    p += (size_t)T_ * 4;
    uint32_t* tpos = (uint32_t*)(ws + p); p += (size_t)T_ * 4;
    ushort_t* xbf  = (ushort_t*)(ws + p); p += (size_t)T_*D_*2;      // bf16 x (16 MB)
    ushort_t* w1t  = (ushort_t*)(ws + p); p += (size_t)E_*H_*D_*2;   // bf16 [E][H][D] (8 MB)
    ushort_t* w2t  = (ushort_t*)(ws + p); p += (size_t)E_*D_*H_*2;   // bf16 [E][D][H] (8 MB)
    ushort_t* hbuf = (ushort_t*)(ws + p); p += ((size_t)2*T_+128)*H_*2; // bf16 (16.5 MB)
    ushort_t* obuf = (ushort_t*)(ws + p);                        // bf16 [2T+128][D] (33 MB)

    (void)hipMemsetAsync(counts, 0, 64, stream);

    transpose_cvt<<<dim3(H_/32, D_/32, E_), 256, 0, stream>>>(w1, w1t, D_, H_);
    transpose_cvt<<<dim3(D_/32, H_/32, E_), 256, 0, stream>>>(w2, w2t, H_, D_);
    gating_kernel<<<T_/4, 256, 0, stream>>>(x, gw, gb, eidx, gsel, xbf);
    bucket_kernel<<<T_/256, 256, 0, stream>>>(eidx, gsel, counts, btok, bgate, tpos);
    prefix_kernel<<<1, 64, 0, stream>>>(counts, offsets);
    mlp1_kernel<<<dim3(T_/64, H_/128, E_), 256, 0, stream>>>(
        xbf, w1t, b1, counts, offsets, btok, hbuf);
    mlp2_kernel<<<dim3(T_/64, D_/128, E_), 256, 0, stream>>>(
        hbuf, w2t, b2, counts, offsets, bgate, obuf);
    combine_kernel<<<T_/2, 256, 0, stream>>>(obuf, tpos, offsets, out);
}